// Round 9
// baseline (215.240 us; speedup 1.0000x reference)
//
#include <hip/hip_runtime.h>
#include <hip/hip_bf16.h>
#include <math.h>

// B=2, L=1024, C=64, R=32, RV=32, DQK=64, H=8, NSINK=4
// x: (2,1024,64,32) fp32; out same. BL = 2048.

typedef __attribute__((ext_vector_type(8))) short short8;
typedef __attribute__((ext_vector_type(4))) short short4v;
typedef __attribute__((ext_vector_type(4))) float float4v;

__device__ __forceinline__ short f2b(float f) {
    __hip_bfloat16 h = __float2bfloat16(f);
    return __builtin_bit_cast(short, h);
}
__device__ __forceinline__ float b2f(short s) {
    unsigned u = ((unsigned)(unsigned short)s) << 16;
    return __builtin_bit_cast(float, u);
}

// ---------------------------------------------------------------------------
// [Wq|Wk] -> transposed bf16 Wt[576][2048]. grid (9 n-tiles, 32 k-tiles)
// ---------------------------------------------------------------------------
__global__ __launch_bounds__(256) void convert_w_kernel(
    const float* __restrict__ Wq, const float* __restrict__ Wk,
    short* __restrict__ Wt)
{
    const int n0 = blockIdx.x * 64;
    const int k0 = blockIdx.y * 64;
    const int tid = threadIdx.x;
    __shared__ float ts[64][65];
    for (int i = tid; i < 4096; i += 256) {
        int kk = i >> 6, nn = i & 63;
        int n = n0 + nn, k = k0 + kk;
        float v = (n < 512) ? Wq[(long)k * 512 + n] : Wk[(long)k * 64 + (n - 512)];
        ts[kk][nn] = v;
    }
    __syncthreads();
    for (int i = tid; i < 4096; i += 256) {
        int nn = i >> 6, kk = i & 63;
        Wt[(long)(n0 + nn) * 2048 + k0 + kk] = f2b(ts[kk][nn]);
    }
}

// ---------------------------------------------------------------------------
// Per-channel value projection -> TRANSPOSED bf16 vt[b][c*32+o][l].
// Also emits xb (bf16 copy of x). grid (C=64, 32 chunks of 64 l)
// ---------------------------------------------------------------------------
__global__ __launch_bounds__(256) void vproj_kernel(
    const float* __restrict__ x, const float* __restrict__ Wv,
    const float* __restrict__ bv, short* __restrict__ vt,
    short* __restrict__ xb)
{
    const int c = blockIdx.x;
    const int chunk = blockIdx.y;       // 0..31
    const int b = chunk >> 4;
    const int l0 = (chunk & 15) * 64;
    const int tid = threadIdx.x;
    __shared__ float Wc[32][33];
    __shared__ float xs[64][33];
    for (int i = tid; i < 1024; i += 256)
        Wc[i >> 5][i & 31] = Wv[(c * 32 + (i >> 5)) * 32 + (i & 31)];
    for (int i = tid; i < 2048; i += 256) {
        int s = i >> 5, r = i & 31;
        long gi = ((long)(b << 10) + l0 + s) * 2048 + c * 32 + r;
        float v = x[gi];
        xs[s][r] = v;
        xb[gi] = f2b(v);
    }
    __syncthreads();
    const int s = tid & 63;
    const int og = tid >> 6;
    #pragma unroll
    for (int oi = 0; oi < 8; ++oi) {
        int o = og * 8 + oi;
        float acc = bv[c * 32 + o];
        #pragma unroll
        for (int r = 0; r < 32; ++r) acc += xs[s][r] * Wc[r][o];
        vt[(long)b * (2048 * 1024) + (long)(c * 32 + o) * 1024 + l0 + s] = f2b(acc);
    }
}

// ---------------------------------------------------------------------------
// qk projection, direct bf16 output with bias: qkb[2048][576] =
// bf16(xb @ Wt^T + bias). 64x64 tile, K-loop 32x64. grid (9, 32)
// ---------------------------------------------------------------------------
__global__ __launch_bounds__(256) void qkproj_kernel(
    const short* __restrict__ xb, const short* __restrict__ Wt,
    const float* __restrict__ bq, const float* __restrict__ bk,
    short* __restrict__ qkb)
{
    __shared__ short As[64][72];
    __shared__ short Bs[64][72];

    const int tid = threadIdx.x;
    const int wave = tid >> 6;
    const int lane = tid & 63;
    const int wm = wave >> 1, wn = wave & 1;
    const int m15 = lane & 15;
    const int quad = lane >> 4;
    const int row0 = blockIdx.y * 64;
    const int col0 = blockIdx.x * 64;

    float4v acc[2][2];
    #pragma unroll
    for (int i = 0; i < 2; ++i)
        #pragma unroll
        for (int j = 0; j < 2; ++j)
            #pragma unroll
            for (int r = 0; r < 4; ++r) acc[i][j][r] = 0.f;

    for (int kt = 0; kt < 32; ++kt) {
        int k0 = kt * 64;
        #pragma unroll
        for (int p = 0; p < 2; ++p) {
            int i = tid + p * 256;
            int m = i >> 3, kq = i & 7;
            *reinterpret_cast<short8*>(&As[m][kq * 8]) =
                *reinterpret_cast<const short8*>(&xb[(long)(row0 + m) * 2048 + k0 + kq * 8]);
        }
        #pragma unroll
        for (int p = 0; p < 2; ++p) {
            int i = tid + p * 256;
            int n = i >> 3, kq = i & 7;
            *reinterpret_cast<short8*>(&Bs[n][kq * 8]) =
                *reinterpret_cast<const short8*>(&Wt[(long)(col0 + n) * 2048 + k0 + kq * 8]);
        }
        __syncthreads();
        #pragma unroll
        for (int ks = 0; ks < 2; ++ks) {
            short8 a[2], b[2];
            #pragma unroll
            for (int t = 0; t < 2; ++t) {
                a[t] = *reinterpret_cast<const short8*>(&As[wm * 32 + t * 16 + m15][ks * 32 + quad * 8]);
                b[t] = *reinterpret_cast<const short8*>(&Bs[wn * 32 + t * 16 + m15][ks * 32 + quad * 8]);
            }
            #pragma unroll
            for (int ti = 0; ti < 2; ++ti)
                #pragma unroll
                for (int tj = 0; tj < 2; ++tj)
                    acc[ti][tj] = __builtin_amdgcn_mfma_f32_16x16x32_bf16(
                        a[ti], b[tj], acc[ti][tj], 0, 0, 0);
        }
        __syncthreads();
    }

    float bias[2];
    #pragma unroll
    for (int tj = 0; tj < 2; ++tj) {
        int col = col0 + wn * 32 + tj * 16 + m15;
        bias[tj] = (col < 512) ? bq[col] : bk[col - 512];
    }
    #pragma unroll
    for (int ti = 0; ti < 2; ++ti)
        #pragma unroll
        for (int r = 0; r < 4; ++r) {
            int row = row0 + wm * 32 + ti * 16 + quad * 4 + r;
            #pragma unroll
            for (int tj = 0; tj < 2; ++tj) {
                int col = col0 + wn * 32 + tj * 16 + m15;
                qkb[(long)row * 576 + col] = f2b(acc[ti][tj][r] + bias[tj]);
            }
        }
}

// ---------------------------------------------------------------------------
// QK^T via MFMA, all 8 heads, bf16 in. S[h,l,s] bf16. grid (16, 16, 2)
// ---------------------------------------------------------------------------
__global__ __launch_bounds__(256) void qk_s_kernel(
    const short* __restrict__ qkb, short* __restrict__ S)
{
    const int s0 = blockIdx.x * 64;
    const int l0 = blockIdx.y * 64;
    const int b = blockIdx.z;
    const int tid = threadIdx.x;
    short* Sz = S + ((long)b << 23);   // 8*1024*1024 per batch

    __shared__ short Qs[64][520];   // 64 l x 512 d (+8 pad)
    __shared__ short Ks[64][72];    // 64 s x 64 d  (+8 pad)

    #pragma unroll
    for (int p = 0; p < 16; ++p) {
        int i = tid + p * 256;
        int row = i >> 6, d8 = i & 63;
        *reinterpret_cast<short8*>(&Qs[row][d8 * 8]) =
            *reinterpret_cast<const short8*>(&qkb[(long)((b << 10) + l0 + row) * 576 + d8 * 8]);
    }
    #pragma unroll
    for (int p = 0; p < 2; ++p) {
        int i = tid + p * 256;
        int row = i >> 3, d8 = i & 7;
        *reinterpret_cast<short8*>(&Ks[row][d8 * 8]) =
            *reinterpret_cast<const short8*>(&qkb[(long)((b << 10) + s0 + row) * 576 + 512 + d8 * 8]);
    }
    __syncthreads();

    const int wave = tid >> 6;
    const int lane = tid & 63;
    const int wm = wave >> 1, wn = wave & 1;
    const int m15 = lane & 15;
    const int quad = lane >> 4;

    for (int h = 0; h < 8; ++h) {
        float4v acc[2][2];
        #pragma unroll
        for (int i = 0; i < 2; ++i)
            #pragma unroll
            for (int j = 0; j < 2; ++j)
                #pragma unroll
                for (int r = 0; r < 4; ++r) acc[i][j][r] = 0.f;

        #pragma unroll
        for (int ks = 0; ks < 2; ++ks) {
            short8 a[2], bfr[2];
            #pragma unroll
            for (int t = 0; t < 2; ++t) {
                a[t]   = *reinterpret_cast<const short8*>(
                    &Qs[wm * 32 + t * 16 + m15][h * 64 + ks * 32 + quad * 8]);
                bfr[t] = *reinterpret_cast<const short8*>(
                    &Ks[wn * 32 + t * 16 + m15][ks * 32 + quad * 8]);
            }
            #pragma unroll
            for (int ti = 0; ti < 2; ++ti)
                #pragma unroll
                for (int tj = 0; tj < 2; ++tj)
                    acc[ti][tj] = __builtin_amdgcn_mfma_f32_16x16x32_bf16(
                        a[ti], bfr[tj], acc[ti][tj], 0, 0, 0);
        }

        #pragma unroll
        for (int ti = 0; ti < 2; ++ti)
            #pragma unroll
            for (int r = 0; r < 4; ++r) {
                int l = l0 + wm * 32 + ti * 16 + quad * 4 + r;
                #pragma unroll
                for (int tj = 0; tj < 2; ++tj) {
                    int s = s0 + wn * 32 + tj * 16 + m15;
                    Sz[((long)h << 20) + (l << 10) + s] = f2b(acc[ti][tj][r] * 0.125f);
                }
            }
    }
}

// ---------------------------------------------------------------------------
// Softmax over s for 8 heads + head-average -> P bf16 [b][l][s]. grid (1024,2)
// ---------------------------------------------------------------------------
__global__ __launch_bounds__(256) void softmax_avg_kernel(
    const short* __restrict__ S, short* __restrict__ P)
{
    const int l = blockIdx.x;
    const int b = blockIdx.y;
    const int tid = threadIdx.x;
    const int h = tid >> 5, j = tid & 31;
    const short* Sz = S + ((long)b << 23);

    __shared__ float es[8][1032];
    __shared__ float invd[8];

    const short* row = &Sz[((long)h << 20) + (l << 10)];
    float vals[32];
    float pm = -1e30f;
    #pragma unroll
    for (int i = 0; i < 32; ++i) {
        float f = b2f(row[i * 32 + j]);
        vals[i] = f;
        pm = fmaxf(pm, f);
    }
    #pragma unroll
    for (int off = 16; off > 0; off >>= 1) pm = fmaxf(pm, __shfl_down(pm, off, 32));
    pm = __shfl(pm, 0, 32);

    float ps = 0.f;
    #pragma unroll
    for (int i = 0; i < 32; ++i) {
        float e = __expf(vals[i] - pm);
        vals[i] = e;
        ps += e;
    }
    #pragma unroll
    for (int off = 16; off > 0; off >>= 1) ps += __shfl_down(ps, off, 32);
    if (j == 0) invd[h] = 1.f / (8.f * ps);
    __syncthreads();

    const float w = invd[h];
    #pragma unroll
    for (int i = 0; i < 32; ++i) es[h][i * 32 + j] = vals[i] * w;
    __syncthreads();

    for (int s = tid; s < 1024; s += 256) {
        float p = 0.f;
        #pragma unroll
        for (int hh = 0; hh < 8; ++hh) p += es[hh][s];
        P[((long)b << 20) + (l << 10) + s] = f2b(p);
    }
}

// ---------------------------------------------------------------------------
// Sink: softmax over l of sink_q.k, atomicAdd (1/32)*attn into Psink[b][l].
// grid 64 = (b, h*4+si)
// ---------------------------------------------------------------------------
__global__ __launch_bounds__(256) void sink_kernel(
    const float* __restrict__ sink_q, const short* __restrict__ qkb,
    float* __restrict__ Psink)
{
    const int z = blockIdx.x;
    const int b = z >> 5;
    const int idx = z & 31;
    const int tid = threadIdx.x;

    __shared__ float sq[64];
    __shared__ float lgl[1024];
    __shared__ float red[4];
    __shared__ float mxs, invs;

    if (tid < 64) sq[tid] = sink_q[idx * 64 + tid];
    __syncthreads();

    float lmax = -1e30f;
    for (int l = tid; l < 1024; l += 256) {
        const short* kp = &qkb[(long)((b << 10) + l) * 576 + 512];
        float acc = 0.f;
        #pragma unroll
        for (int d8 = 0; d8 < 8; ++d8) {
            short8 kv = *reinterpret_cast<const short8*>(&kp[d8 * 8]);
            #pragma unroll
            for (int j = 0; j < 8; ++j) acc += b2f(kv[j]) * sq[d8 * 8 + j];
        }
        acc *= 0.125f;
        lgl[l] = acc;
        lmax = fmaxf(lmax, acc);
    }
    #pragma unroll
    for (int off = 32; off > 0; off >>= 1) lmax = fmaxf(lmax, __shfl_down(lmax, off, 64));
    if ((tid & 63) == 0) red[tid >> 6] = lmax;
    __syncthreads();
    if (tid == 0) mxs = fmaxf(fmaxf(red[0], red[1]), fmaxf(red[2], red[3]));
    __syncthreads();

    const float m = mxs;
    float psum = 0.f;
    for (int l = tid; l < 1024; l += 256) {
        float e = __expf(lgl[l] - m);
        lgl[l] = e;
        psum += e;
    }
    #pragma unroll
    for (int off = 32; off > 0; off >>= 1) psum += __shfl_down(psum, off, 64);
    if ((tid & 63) == 0) red[tid >> 6] = psum;
    __syncthreads();
    if (tid == 0) invs = 1.f / (red[0] + red[1] + red[2] + red[3]);
    __syncthreads();

    const float wgt = invs * (1.f / 32.f);
    for (int l = tid; l < 1024; l += 256)
        atomicAdd(&Psink[(b << 10) + l], lgl[l] * wgt);
}

// ---------------------------------------------------------------------------
// Ysink[b][co] = sum_l Psink[b][l] * vt[b][co][l]. grid (512, 2), wave per co.
// ---------------------------------------------------------------------------
__global__ __launch_bounds__(256) void sinky_kernel(
    const float* __restrict__ Psink, const short* __restrict__ vt,
    float* __restrict__ Ysink)
{
    const int b = blockIdx.y;
    const int tid = threadIdx.x;
    __shared__ float ps[1024];
    {
        float4 v = reinterpret_cast<const float4*>(&Psink[b << 10])[tid];
        *reinterpret_cast<float4*>(&ps[tid * 4]) = v;
    }
    __syncthreads();
    const int wave = tid >> 6;
    const int lane = tid & 63;
    const int co = blockIdx.x * 4 + wave;
    const short* vp = &vt[((long)b * 2048 + co) * 1024];
    float acc = 0.f;
    #pragma unroll
    for (int t = 0; t < 16; ++t) {
        int l = t * 64 + lane;
        acc += ps[l] * b2f(vp[l]);
    }
    #pragma unroll
    for (int off = 32; off > 0; off >>= 1) acc += __shfl_down(acc, off, 64);
    if (lane == 0) Ysink[(b << 11) + co] = acc;
}

// ---------------------------------------------------------------------------
// Fused Y-GEMM + MFMA output projection, 128x64 tile:
//  Ytile[128l x 64co] = P[b] @ vt[b]^T          (bf16 MFMA, K=1024)
//  out[128l x 64cr]   = x + bo + (Yt+Ysink) @ blockdiag(Wo)   (2nd MFMA pass)
// grid (32 co-tiles, 8 l-tiles, 2 b)
// ---------------------------------------------------------------------------
__global__ __launch_bounds__(256) void y_fused_kernel(
    const short* __restrict__ P, const short* __restrict__ vt,
    const float* __restrict__ Ysink, const float* __restrict__ Wo,
    const float* __restrict__ bo, const float* __restrict__ x,
    float* __restrict__ out)
{
    __shared__ short As[128][72];
    __shared__ short Bs[64][72];

    const int tid = threadIdx.x;
    const int b = blockIdx.z;
    const int col0 = blockIdx.x * 64;
    const int row0 = blockIdx.y * 128;
    const short* Pz = P + ((long)b << 20);
    const short* Vz = vt + ((long)b * 2048 * 1024);

    const int wave = tid >> 6;
    const int lane = tid & 63;
    const int wm = wave >> 1, wn = wave & 1;
    const int m15 = lane & 15;
    const int quad = lane >> 4;

    float4v acc[4][2];
    #pragma unroll
    for (int i = 0; i < 4; ++i)
        #pragma unroll
        for (int j = 0; j < 2; ++j)
            #pragma unroll
            for (int r = 0; r < 4; ++r) acc[i][j][r] = 0.f;

    for (int kt = 0; kt < 16; ++kt) {
        int k0 = kt * 64;
        #pragma unroll
        for (int p = 0; p < 4; ++p) {
            int i = tid + p * 256;
            int m = i >> 3, kq = i & 7;
            *reinterpret_cast<short8*>(&As[m][kq * 8]) =
                *reinterpret_cast<const short8*>(&Pz[(long)(row0 + m) * 1024 + k0 + kq * 8]);
        }
        #pragma unroll
        for (int p = 0; p < 2; ++p) {
            int i = tid + p * 256;
            int n = i >> 3, kq = i & 7;
            *reinterpret_cast<short8*>(&Bs[n][kq * 8]) =
                *reinterpret_cast<const short8*>(&Vz[(long)(col0 + n) * 1024 + k0 + kq * 8]);
        }
        __syncthreads();
        #pragma unroll
        for (int ks = 0; ks < 2; ++ks) {
            short8 a[4], bb[2];
            #pragma unroll
            for (int t = 0; t < 4; ++t)
                a[t] = *reinterpret_cast<const short8*>(&As[wm * 64 + t * 16 + m15][ks * 32 + quad * 8]);
            #pragma unroll
            for (int t = 0; t < 2; ++t)
                bb[t] = *reinterpret_cast<const short8*>(&Bs[wn * 32 + t * 16 + m15][ks * 32 + quad * 8]);
            #pragma unroll
            for (int ti = 0; ti < 4; ++ti)
                #pragma unroll
                for (int tj = 0; tj < 2; ++tj)
                    acc[ti][tj] = __builtin_amdgcn_mfma_f32_16x16x32_bf16(
                        a[ti], bb[tj], acc[ti][tj], 0, 0, 0);
        }
        __syncthreads();
    }

    // ---- epilogue pass 2: out = x + bo + (Yt + Ysink) @ blockdiag(Wo) ----
    float ysv[2];
    #pragma unroll
    for (int tj = 0; tj < 2; ++tj)
        ysv[tj] = Ysink[(b << 11) + col0 + wn * 32 + tj * 16 + m15];

    #pragma unroll
    for (int ti = 0; ti < 4; ++ti)
        #pragma unroll
        for (int r = 0; r < 4; ++r) {
            int row = wm * 64 + ti * 16 + quad * 4 + r;
            #pragma unroll
            for (int tj = 0; tj < 2; ++tj) {
                int col = wn * 32 + tj * 16 + m15;
                As[row][col] = f2b(acc[ti][tj][r] + ysv[tj]);
            }
        }
    // WoB[n][k] = (same channel) ? Wo[c0 + n/32][o=k&31][r=n&31] : 0
    const int c0 = col0 >> 5;
    for (int i = tid; i < 4096; i += 256) {
        int n = i >> 6, k = i & 63;
        short v = 0;
        if ((n >> 5) == (k >> 5))
            v = f2b(Wo[((long)(c0 + (n >> 5)) * 32 + (k & 31)) * 32 + (n & 31)]);
        Bs[n][k] = v;
    }
    __syncthreads();

    float4v acc2[4][2];
    #pragma unroll
    for (int i = 0; i < 4; ++i)
        #pragma unroll
        for (int j = 0; j < 2; ++j)
            #pragma unroll
            for (int r = 0; r < 4; ++r) acc2[i][j][r] = 0.f;

    #pragma unroll
    for (int ks = 0; ks < 2; ++ks) {
        short8 a[4], bb[2];
        #pragma unroll
        for (int t = 0; t < 4; ++t)
            a[t] = *reinterpret_cast<const short8*>(&As[wm * 64 + t * 16 + m15][ks * 32 + quad * 8]);
        #pragma unroll
        for (int t = 0; t < 2; ++t)
            bb[t] = *reinterpret_cast<const short8*>(&Bs[wn * 32 + t * 16 + m15][ks * 32 + quad * 8]);
        #pragma unroll
        for (int ti = 0; ti < 4; ++ti)
            #pragma unroll
            for (int tj = 0; tj < 2; ++tj)
                acc2[ti][tj] = __builtin_amdgcn_mfma_f32_16x16x32_bf16(
                    a[ti], bb[tj], acc2[ti][tj], 0, 0, 0);
    }

    float bov[2];
    #pragma unroll
    for (int tj = 0; tj < 2; ++tj)
        bov[tj] = bo[col0 + wn * 32 + tj * 16 + m15];

    #pragma unroll
    for (int ti = 0; ti < 4; ++ti)
        #pragma unroll
        for (int r = 0; r < 4; ++r) {
            int row = (b << 10) + row0 + wm * 64 + ti * 16 + quad * 4 + r;
            #pragma unroll
            for (int tj = 0; tj < 2; ++tj) {
                int col = col0 + wn * 32 + tj * 16 + m15;
                long oi = (long)row * 2048 + col;
                out[oi] = x[oi] + bov[tj] + acc2[ti][tj][r];
            }
        }
}

// ---------------------------------------------------------------------------
extern "C" void kernel_launch(void* const* d_in, const int* in_sizes, int n_in,
                              void* d_out, int out_size, void* d_ws, size_t ws_size,
                              hipStream_t stream)
{
    const float* x  = (const float*)d_in[0];
    const float* Wq = (const float*)d_in[1];
    const float* bq = (const float*)d_in[2];
    const float* Wk = (const float*)d_in[3];
    const float* bk = (const float*)d_in[4];
    const float* Wv = (const float*)d_in[5];
    const float* bv = (const float*)d_in[6];
    const float* Wo = (const float*)d_in[7];
    const float* bo = (const float*)d_in[8];
    const float* sq = (const float*)d_in[9];
    float* out = (float*)d_out;

    // workspace layout (float units), total ~48.5 MB
    float* ws = (float*)d_ws;
    short* qkb    = (short*)ws;                  //   589,824 f (bf16 2048x576)
    short* P      = (short*)(ws + 589824);       // 1,048,576 f (2x1024x1024 bf16)
    float* Psink  = ws + 1638400;                //     2,048 f
    short* vt     = (short*)(ws + 1640448);      // 2,097,152 f (bf16)
    float* Ysink  = ws + 3737600;                //     4,096 f
    float* region = ws + 3741696;                // shared: {xb,Wt} -> Sb
    short* xb     = (short*)region;              // 2,097,152 f (bf16)
    short* Wt     = (short*)(region + 2097152);  //   589,824 f (bf16)
    short* Sb     = (short*)region;              // 2 x 8M bf16 = 8,388,608 f

    dim3 blk(256);

    hipMemsetAsync(Psink, 0, 2048 * sizeof(float), stream);
    convert_w_kernel<<<dim3(9, 32), blk, 0, stream>>>(Wq, Wk, Wt);
    vproj_kernel<<<dim3(64, 32), blk, 0, stream>>>(x, Wv, bv, vt, xb);
    qkproj_kernel<<<dim3(9, 32), blk, 0, stream>>>(xb, Wt, bq, bk, qkb);
    qk_s_kernel<<<dim3(16, 16, 2), blk, 0, stream>>>(qkb, Sb);
    softmax_avg_kernel<<<dim3(1024, 2), blk, 0, stream>>>(Sb, P);
    sink_kernel<<<dim3(64), blk, 0, stream>>>(sq, qkb, Psink);
    sinky_kernel<<<dim3(512, 2), blk, 0, stream>>>(Psink, vt, Ysink);
    y_fused_kernel<<<dim3(32, 8, 2), blk, 0, stream>>>(
        P, vt, Ysink, Wo, bo, x, out);
}

// Round 10
// 185.514 us; speedup vs baseline: 1.1602x; 1.1602x over previous
//
#include <hip/hip_runtime.h>
#include <hip/hip_bf16.h>
#include <math.h>

// B=2, L=1024, C=64, R=32, RV=32, DQK=64, H=8, NSINK=4
// x: (2,1024,64,32) fp32; out same. BL = 2048.

typedef __attribute__((ext_vector_type(8))) short short8;
typedef __attribute__((ext_vector_type(4))) short short4v;
typedef __attribute__((ext_vector_type(4))) float float4v;

__device__ __forceinline__ short f2b(float f) {
    __hip_bfloat16 h = __float2bfloat16(f);
    return __builtin_bit_cast(short, h);
}
__device__ __forceinline__ float b2f(short s) {
    unsigned u = ((unsigned)(unsigned short)s) << 16;
    return __builtin_bit_cast(float, u);
}

// ---------------------------------------------------------------------------
// [Wq|Wk] -> transposed bf16 Wt[576][2048]. grid (9 n-tiles, 32 k-tiles).
// Block (0,0) also zero-inits Psink (runs before sink_kernel in stream order).
// ---------------------------------------------------------------------------
__global__ __launch_bounds__(256) void convert_w_kernel(
    const float* __restrict__ Wq, const float* __restrict__ Wk,
    short* __restrict__ Wt, float* __restrict__ Psink)
{
    const int n0 = blockIdx.x * 64;
    const int k0 = blockIdx.y * 64;
    const int tid = threadIdx.x;
    if (blockIdx.x == 0 && blockIdx.y == 0) {
        #pragma unroll
        for (int p = 0; p < 8; ++p) Psink[p * 256 + tid] = 0.f;
    }
    __shared__ float ts[64][65];
    for (int i = tid; i < 4096; i += 256) {
        int kk = i >> 6, nn = i & 63;
        int n = n0 + nn, k = k0 + kk;
        float v = (n < 512) ? Wq[(long)k * 512 + n] : Wk[(long)k * 64 + (n - 512)];
        ts[kk][nn] = v;
    }
    __syncthreads();
    for (int i = tid; i < 4096; i += 256) {
        int nn = i >> 6, kk = i & 63;
        Wt[(long)(n0 + nn) * 2048 + k0 + kk] = f2b(ts[kk][nn]);
    }
}

// ---------------------------------------------------------------------------
// Per-channel value projection -> TRANSPOSED bf16 vt[b][c*32+o][l].
// Also emits xb (bf16 copy of x). grid (C=64, 32 chunks of 64 l)
// ---------------------------------------------------------------------------
__global__ __launch_bounds__(256) void vproj_kernel(
    const float* __restrict__ x, const float* __restrict__ Wv,
    const float* __restrict__ bv, short* __restrict__ vt,
    short* __restrict__ xb)
{
    const int c = blockIdx.x;
    const int chunk = blockIdx.y;       // 0..31
    const int b = chunk >> 4;
    const int l0 = (chunk & 15) * 64;
    const int tid = threadIdx.x;
    __shared__ float Wc[32][33];
    __shared__ float xs[64][33];
    for (int i = tid; i < 1024; i += 256)
        Wc[i >> 5][i & 31] = Wv[(c * 32 + (i >> 5)) * 32 + (i & 31)];
    for (int i = tid; i < 2048; i += 256) {
        int s = i >> 5, r = i & 31;
        long gi = ((long)(b << 10) + l0 + s) * 2048 + c * 32 + r;
        float v = x[gi];
        xs[s][r] = v;
        xb[gi] = f2b(v);
    }
    __syncthreads();
    const int s = tid & 63;
    const int og = tid >> 6;
    #pragma unroll
    for (int oi = 0; oi < 8; ++oi) {
        int o = og * 8 + oi;
        float acc = bv[c * 32 + o];
        #pragma unroll
        for (int r = 0; r < 32; ++r) acc += xs[s][r] * Wc[r][o];
        vt[(long)b * (2048 * 1024) + (long)(c * 32 + o) * 1024 + l0 + s] = f2b(acc);
    }
}

// ---------------------------------------------------------------------------
// qk projection, split-K=4, no atomics: qkpart[z][2048][576] = partial GEMM.
// 64x64 tile, K=512 per block. grid (9, 32, 4)
// ---------------------------------------------------------------------------
__global__ __launch_bounds__(256) void qkproj_kernel(
    const short* __restrict__ xb, const short* __restrict__ Wt,
    float* __restrict__ qkpart)
{
    __shared__ short As[64][72];
    __shared__ short Bs[64][72];

    const int tid = threadIdx.x;
    const int wave = tid >> 6;
    const int lane = tid & 63;
    const int wm = wave >> 1, wn = wave & 1;
    const int m15 = lane & 15;
    const int quad = lane >> 4;
    const int row0 = blockIdx.y * 64;
    const int col0 = blockIdx.x * 64;
    const int kbase = blockIdx.z * 512;
    float* outz = qkpart + (long)blockIdx.z * 1179648;

    float4v acc[2][2];
    #pragma unroll
    for (int i = 0; i < 2; ++i)
        #pragma unroll
        for (int j = 0; j < 2; ++j)
            #pragma unroll
            for (int r = 0; r < 4; ++r) acc[i][j][r] = 0.f;

    for (int kt = 0; kt < 8; ++kt) {
        int k0 = kbase + kt * 64;
        #pragma unroll
        for (int p = 0; p < 2; ++p) {
            int i = tid + p * 256;
            int m = i >> 3, kq = i & 7;
            *reinterpret_cast<short8*>(&As[m][kq * 8]) =
                *reinterpret_cast<const short8*>(&xb[(long)(row0 + m) * 2048 + k0 + kq * 8]);
        }
        #pragma unroll
        for (int p = 0; p < 2; ++p) {
            int i = tid + p * 256;
            int n = i >> 3, kq = i & 7;
            *reinterpret_cast<short8*>(&Bs[n][kq * 8]) =
                *reinterpret_cast<const short8*>(&Wt[(long)(col0 + n) * 2048 + k0 + kq * 8]);
        }
        __syncthreads();
        #pragma unroll
        for (int ks = 0; ks < 2; ++ks) {
            short8 a[2], b[2];
            #pragma unroll
            for (int t = 0; t < 2; ++t) {
                a[t] = *reinterpret_cast<const short8*>(&As[wm * 32 + t * 16 + m15][ks * 32 + quad * 8]);
                b[t] = *reinterpret_cast<const short8*>(&Bs[wn * 32 + t * 16 + m15][ks * 32 + quad * 8]);
            }
            #pragma unroll
            for (int ti = 0; ti < 2; ++ti)
                #pragma unroll
                for (int tj = 0; tj < 2; ++tj)
                    acc[ti][tj] = __builtin_amdgcn_mfma_f32_16x16x32_bf16(
                        a[ti], b[tj], acc[ti][tj], 0, 0, 0);
        }
        __syncthreads();
    }

    #pragma unroll
    for (int ti = 0; ti < 2; ++ti)
        #pragma unroll
        for (int r = 0; r < 4; ++r) {
            int row = row0 + wm * 32 + ti * 16 + quad * 4 + r;
            #pragma unroll
            for (int tj = 0; tj < 2; ++tj) {
                int col = col0 + wn * 32 + tj * 16 + m15;
                outz[(long)row * 576 + col] = acc[ti][tj][r];
            }
        }
}

// ---------------------------------------------------------------------------
// qkb = bf16( sum_z qkpart[z] + bias(bq|bk) ). grid 1152, float4/thread.
// ---------------------------------------------------------------------------
__global__ __launch_bounds__(256) void convert_qk_kernel(
    const float* __restrict__ qkpart, const float* __restrict__ bq,
    const float* __restrict__ bk, short* __restrict__ qkb)
{
    int id = blockIdx.x * 256 + threadIdx.x;   // < 294912
    float4 a0 = reinterpret_cast<const float4*>(qkpart)[id];
    float4 a1 = reinterpret_cast<const float4*>(qkpart + 1179648)[id];
    float4 a2 = reinterpret_cast<const float4*>(qkpart + 2359296)[id];
    float4 a3 = reinterpret_cast<const float4*>(qkpart + 3538944)[id];
    int col4 = (id % 144) * 4;
    float4 bias = (col4 < 512)
        ? *reinterpret_cast<const float4*>(&bq[col4])
        : *reinterpret_cast<const float4*>(&bk[col4 - 512]);
    short4v o;
    o[0] = f2b(a0.x + a1.x + a2.x + a3.x + bias.x);
    o[1] = f2b(a0.y + a1.y + a2.y + a3.y + bias.y);
    o[2] = f2b(a0.z + a1.z + a2.z + a3.z + bias.z);
    o[3] = f2b(a0.w + a1.w + a2.w + a3.w + bias.w);
    reinterpret_cast<short4v*>(qkb)[id] = o;
}

// ---------------------------------------------------------------------------
// QK^T via MFMA, all 8 heads, bf16 in. S[h,l,s] bf16. grid (16, 16, 2)
// ---------------------------------------------------------------------------
__global__ __launch_bounds__(256) void qk_s_kernel(
    const short* __restrict__ qkb, short* __restrict__ S)
{
    const int s0 = blockIdx.x * 64;
    const int l0 = blockIdx.y * 64;
    const int b = blockIdx.z;
    const int tid = threadIdx.x;
    short* Sz = S + ((long)b << 23);   // 8*1024*1024 per batch

    __shared__ short Qs[64][520];   // 64 l x 512 d (+8 pad)
    __shared__ short Ks[64][72];    // 64 s x 64 d  (+8 pad)

    #pragma unroll
    for (int p = 0; p < 16; ++p) {
        int i = tid + p * 256;
        int row = i >> 6, d8 = i & 63;
        *reinterpret_cast<short8*>(&Qs[row][d8 * 8]) =
            *reinterpret_cast<const short8*>(&qkb[(long)((b << 10) + l0 + row) * 576 + d8 * 8]);
    }
    #pragma unroll
    for (int p = 0; p < 2; ++p) {
        int i = tid + p * 256;
        int row = i >> 3, d8 = i & 7;
        *reinterpret_cast<short8*>(&Ks[row][d8 * 8]) =
            *reinterpret_cast<const short8*>(&qkb[(long)((b << 10) + s0 + row) * 576 + 512 + d8 * 8]);
    }
    __syncthreads();

    const int wave = tid >> 6;
    const int lane = tid & 63;
    const int wm = wave >> 1, wn = wave & 1;
    const int m15 = lane & 15;
    const int quad = lane >> 4;

    for (int h = 0; h < 8; ++h) {
        float4v acc[2][2];
        #pragma unroll
        for (int i = 0; i < 2; ++i)
            #pragma unroll
            for (int j = 0; j < 2; ++j)
                #pragma unroll
                for (int r = 0; r < 4; ++r) acc[i][j][r] = 0.f;

        #pragma unroll
        for (int ks = 0; ks < 2; ++ks) {
            short8 a[2], bfr[2];
            #pragma unroll
            for (int t = 0; t < 2; ++t) {
                a[t]   = *reinterpret_cast<const short8*>(
                    &Qs[wm * 32 + t * 16 + m15][h * 64 + ks * 32 + quad * 8]);
                bfr[t] = *reinterpret_cast<const short8*>(
                    &Ks[wn * 32 + t * 16 + m15][ks * 32 + quad * 8]);
            }
            #pragma unroll
            for (int ti = 0; ti < 2; ++ti)
                #pragma unroll
                for (int tj = 0; tj < 2; ++tj)
                    acc[ti][tj] = __builtin_amdgcn_mfma_f32_16x16x32_bf16(
                        a[ti], bfr[tj], acc[ti][tj], 0, 0, 0);
        }

        #pragma unroll
        for (int ti = 0; ti < 2; ++ti)
            #pragma unroll
            for (int r = 0; r < 4; ++r) {
                int l = l0 + wm * 32 + ti * 16 + quad * 4 + r;
                #pragma unroll
                for (int tj = 0; tj < 2; ++tj) {
                    int s = s0 + wn * 32 + tj * 16 + m15;
                    Sz[((long)h << 20) + (l << 10) + s] = f2b(acc[ti][tj][r] * 0.125f);
                }
            }
    }
}

// ---------------------------------------------------------------------------
// Softmax over s for 8 heads + head-average -> P bf16 [b][l][s]. grid (1024,2)
// ---------------------------------------------------------------------------
__global__ __launch_bounds__(256) void softmax_avg_kernel(
    const short* __restrict__ S, short* __restrict__ P)
{
    const int l = blockIdx.x;
    const int b = blockIdx.y;
    const int tid = threadIdx.x;
    const int h = tid >> 5, j = tid & 31;
    const short* Sz = S + ((long)b << 23);

    __shared__ float es[8][1032];
    __shared__ float invd[8];

    const short* row = &Sz[((long)h << 20) + (l << 10)];
    float vals[32];
    float pm = -1e30f;
    #pragma unroll
    for (int i = 0; i < 32; ++i) {
        float f = b2f(row[i * 32 + j]);
        vals[i] = f;
        pm = fmaxf(pm, f);
    }
    #pragma unroll
    for (int off = 16; off > 0; off >>= 1) pm = fmaxf(pm, __shfl_down(pm, off, 32));
    pm = __shfl(pm, 0, 32);

    float ps = 0.f;
    #pragma unroll
    for (int i = 0; i < 32; ++i) {
        float e = __expf(vals[i] - pm);
        vals[i] = e;
        ps += e;
    }
    #pragma unroll
    for (int off = 16; off > 0; off >>= 1) ps += __shfl_down(ps, off, 32);
    if (j == 0) invd[h] = 1.f / (8.f * ps);
    __syncthreads();

    const float w = invd[h];
    #pragma unroll
    for (int i = 0; i < 32; ++i) es[h][i * 32 + j] = vals[i] * w;
    __syncthreads();

    for (int s = tid; s < 1024; s += 256) {
        float p = 0.f;
        #pragma unroll
        for (int hh = 0; hh < 8; ++hh) p += es[hh][s];
        P[((long)b << 20) + (l << 10) + s] = f2b(p);
    }
}

// ---------------------------------------------------------------------------
// Sink: softmax over l of sink_q.k, atomicAdd (1/32)*attn into Psink[b][l].
// grid 64 = (b, h*4+si)
// ---------------------------------------------------------------------------
__global__ __launch_bounds__(256) void sink_kernel(
    const float* __restrict__ sink_q, const short* __restrict__ qkb,
    float* __restrict__ Psink)
{
    const int z = blockIdx.x;
    const int b = z >> 5;
    const int idx = z & 31;
    const int tid = threadIdx.x;

    __shared__ float sq[64];
    __shared__ float lgl[1024];
    __shared__ float red[4];
    __shared__ float mxs, invs;

    if (tid < 64) sq[tid] = sink_q[idx * 64 + tid];
    __syncthreads();

    float lmax = -1e30f;
    for (int l = tid; l < 1024; l += 256) {
        const short* kp = &qkb[(long)((b << 10) + l) * 576 + 512];
        float acc = 0.f;
        #pragma unroll
        for (int d8 = 0; d8 < 8; ++d8) {
            short8 kv = *reinterpret_cast<const short8*>(&kp[d8 * 8]);
            #pragma unroll
            for (int j = 0; j < 8; ++j) acc += b2f(kv[j]) * sq[d8 * 8 + j];
        }
        acc *= 0.125f;
        lgl[l] = acc;
        lmax = fmaxf(lmax, acc);
    }
    #pragma unroll
    for (int off = 32; off > 0; off >>= 1) lmax = fmaxf(lmax, __shfl_down(lmax, off, 64));
    if ((tid & 63) == 0) red[tid >> 6] = lmax;
    __syncthreads();
    if (tid == 0) mxs = fmaxf(fmaxf(red[0], red[1]), fmaxf(red[2], red[3]));
    __syncthreads();

    const float m = mxs;
    float psum = 0.f;
    for (int l = tid; l < 1024; l += 256) {
        float e = __expf(lgl[l] - m);
        lgl[l] = e;
        psum += e;
    }
    #pragma unroll
    for (int off = 32; off > 0; off >>= 1) psum += __shfl_down(psum, off, 64);
    if ((tid & 63) == 0) red[tid >> 6] = psum;
    __syncthreads();
    if (tid == 0) invs = 1.f / (red[0] + red[1] + red[2] + red[3]);
    __syncthreads();

    const float wgt = invs * (1.f / 32.f);
    for (int l = tid; l < 1024; l += 256)
        atomicAdd(&Psink[(b << 10) + l], lgl[l] * wgt);
}

// ---------------------------------------------------------------------------
// Ysink[b][co] = sum_l Psink[b][l] * vt[b][co][l]. grid (512, 2), wave per co.
// ---------------------------------------------------------------------------
__global__ __launch_bounds__(256) void sinky_kernel(
    const float* __restrict__ Psink, const short* __restrict__ vt,
    float* __restrict__ Ysink)
{
    const int b = blockIdx.y;
    const int tid = threadIdx.x;
    __shared__ float ps[1024];
    {
        float4 v = reinterpret_cast<const float4*>(&Psink[b << 10])[tid];
        *reinterpret_cast<float4*>(&ps[tid * 4]) = v;
    }
    __syncthreads();
    const int wave = tid >> 6;
    const int lane = tid & 63;
    const int co = blockIdx.x * 4 + wave;
    const short* vp = &vt[((long)b * 2048 + co) * 1024];
    float acc = 0.f;
    #pragma unroll
    for (int t = 0; t < 16; ++t) {
        int l = t * 64 + lane;
        acc += ps[l] * b2f(vp[l]);
    }
    #pragma unroll
    for (int off = 32; off > 0; off >>= 1) acc += __shfl_down(acc, off, 64);
    if (lane == 0) Ysink[(b << 11) + co] = acc;
}

// ---------------------------------------------------------------------------
// Fused Y-GEMM + MFMA output projection, 128x64 tile:
//  Ytile[128l x 64co] = P[b] @ vt[b]^T          (bf16 MFMA, K=1024)
//  out[128l x 64cr]   = x + bo + (Yt+Ysink) @ blockdiag(Wo)   (2nd MFMA pass)
// grid (32 co-tiles, 8 l-tiles, 2 b)
// ---------------------------------------------------------------------------
__global__ __launch_bounds__(256) void y_fused_kernel(
    const short* __restrict__ P, const short* __restrict__ vt,
    const float* __restrict__ Ysink, const float* __restrict__ Wo,
    const float* __restrict__ bo, const float* __restrict__ x,
    float* __restrict__ out)
{
    __shared__ short As[128][72];
    __shared__ short Bs[64][72];

    const int tid = threadIdx.x;
    const int b = blockIdx.z;
    const int col0 = blockIdx.x * 64;
    const int row0 = blockIdx.y * 128;
    const short* Pz = P + ((long)b << 20);
    const short* Vz = vt + ((long)b * 2048 * 1024);

    const int wave = tid >> 6;
    const int lane = tid & 63;
    const int wm = wave >> 1, wn = wave & 1;
    const int m15 = lane & 15;
    const int quad = lane >> 4;

    float4v acc[4][2];
    #pragma unroll
    for (int i = 0; i < 4; ++i)
        #pragma unroll
        for (int j = 0; j < 2; ++j)
            #pragma unroll
            for (int r = 0; r < 4; ++r) acc[i][j][r] = 0.f;

    for (int kt = 0; kt < 16; ++kt) {
        int k0 = kt * 64;
        #pragma unroll
        for (int p = 0; p < 4; ++p) {
            int i = tid + p * 256;
            int m = i >> 3, kq = i & 7;
            *reinterpret_cast<short8*>(&As[m][kq * 8]) =
                *reinterpret_cast<const short8*>(&Pz[(long)(row0 + m) * 1024 + k0 + kq * 8]);
        }
        #pragma unroll
        for (int p = 0; p < 2; ++p) {
            int i = tid + p * 256;
            int n = i >> 3, kq = i & 7;
            *reinterpret_cast<short8*>(&Bs[n][kq * 8]) =
                *reinterpret_cast<const short8*>(&Vz[(long)(col0 + n) * 1024 + k0 + kq * 8]);
        }
        __syncthreads();
        #pragma unroll
        for (int ks = 0; ks < 2; ++ks) {
            short8 a[4], bb[2];
            #pragma unroll
            for (int t = 0; t < 4; ++t)
                a[t] = *reinterpret_cast<const short8*>(&As[wm * 64 + t * 16 + m15][ks * 32 + quad * 8]);
            #pragma unroll
            for (int t = 0; t < 2; ++t)
                bb[t] = *reinterpret_cast<const short8*>(&Bs[wn * 32 + t * 16 + m15][ks * 32 + quad * 8]);
            #pragma unroll
            for (int ti = 0; ti < 4; ++ti)
                #pragma unroll
                for (int tj = 0; tj < 2; ++tj)
                    acc[ti][tj] = __builtin_amdgcn_mfma_f32_16x16x32_bf16(
                        a[ti], bb[tj], acc[ti][tj], 0, 0, 0);
        }
        __syncthreads();
    }

    // ---- epilogue pass 2: out = x + bo + (Yt + Ysink) @ blockdiag(Wo) ----
    float ysv[2];
    #pragma unroll
    for (int tj = 0; tj < 2; ++tj)
        ysv[tj] = Ysink[(b << 11) + col0 + wn * 32 + tj * 16 + m15];

    #pragma unroll
    for (int ti = 0; ti < 4; ++ti)
        #pragma unroll
        for (int r = 0; r < 4; ++r) {
            int row = wm * 64 + ti * 16 + quad * 4 + r;
            #pragma unroll
            for (int tj = 0; tj < 2; ++tj) {
                int col = wn * 32 + tj * 16 + m15;
                As[row][col] = f2b(acc[ti][tj][r] + ysv[tj]);
            }
        }
    // WoB[n][k] = (same channel) ? Wo[c0 + n/32][o=k&31][r=n&31] : 0
    const int c0 = col0 >> 5;
    for (int i = tid; i < 4096; i += 256) {
        int n = i >> 6, k = i & 63;
        short v = 0;
        if ((n >> 5) == (k >> 5))
            v = f2b(Wo[((long)(c0 + (n >> 5)) * 32 + (k & 31)) * 32 + (n & 31)]);
        Bs[n][k] = v;
    }
    __syncthreads();

    float4v acc2[4][2];
    #pragma unroll
    for (int i = 0; i < 4; ++i)
        #pragma unroll
        for (int j = 0; j < 2; ++j)
            #pragma unroll
            for (int r = 0; r < 4; ++r) acc2[i][j][r] = 0.f;

    #pragma unroll
    for (int ks = 0; ks < 2; ++ks) {
        short8 a[4], bb[2];
        #pragma unroll
        for (int t = 0; t < 4; ++t)
            a[t] = *reinterpret_cast<const short8*>(&As[wm * 64 + t * 16 + m15][ks * 32 + quad * 8]);
        #pragma unroll
        for (int t = 0; t < 2; ++t)
            bb[t] = *reinterpret_cast<const short8*>(&Bs[wn * 32 + t * 16 + m15][ks * 32 + quad * 8]);
        #pragma unroll
        for (int ti = 0; ti < 4; ++ti)
            #pragma unroll
            for (int tj = 0; tj < 2; ++tj)
                acc2[ti][tj] = __builtin_amdgcn_mfma_f32_16x16x32_bf16(
                    a[ti], bb[tj], acc2[ti][tj], 0, 0, 0);
    }

    float bov[2];
    #pragma unroll
    for (int tj = 0; tj < 2; ++tj)
        bov[tj] = bo[col0 + wn * 32 + tj * 16 + m15];

    #pragma unroll
    for (int ti = 0; ti < 4; ++ti)
        #pragma unroll
        for (int r = 0; r < 4; ++r) {
            int row = (b << 10) + row0 + wm * 64 + ti * 16 + quad * 4 + r;
            #pragma unroll
            for (int tj = 0; tj < 2; ++tj) {
                int col = col0 + wn * 32 + tj * 16 + m15;
                long oi = (long)row * 2048 + col;
                out[oi] = x[oi] + bov[tj] + acc2[ti][tj][r];
            }
        }
}

// ---------------------------------------------------------------------------
extern "C" void kernel_launch(void* const* d_in, const int* in_sizes, int n_in,
                              void* d_out, int out_size, void* d_ws, size_t ws_size,
                              hipStream_t stream)
{
    const float* x  = (const float*)d_in[0];
    const float* Wq = (const float*)d_in[1];
    const float* bq = (const float*)d_in[2];
    const float* Wk = (const float*)d_in[3];
    const float* bk = (const float*)d_in[4];
    const float* Wv = (const float*)d_in[5];
    const float* bv = (const float*)d_in[6];
    const float* Wo = (const float*)d_in[7];
    const float* bo = (const float*)d_in[8];
    const float* sq = (const float*)d_in[9];
    float* out = (float*)d_out;

    // workspace layout (float units), total ~67 MB
    float* ws = (float*)d_ws;
    float* qkpart = ws;                          // 4 x 2048x576 fp32 = 4,718,592
    short* qkb    = (short*)(ws + 4718592);      //   589,824 f (bf16)
    short* P      = (short*)(ws + 5308416);      // 1,048,576 f (2x1024x1024 bf16)
    float* Psink  = ws + 6356992;                //     2,048 f
    short* vt     = (short*)(ws + 6359040);      // 2,097,152 f (bf16)
    float* Ysink  = ws + 8456192;                //     4,096 f
    float* region = ws + 8460288;                // shared: {xb,Wt} -> Sb
    short* xb     = (short*)region;              // 2,097,152 f (bf16)
    short* Wt     = (short*)(region + 2097152);  //   589,824 f (bf16)
    short* Sb     = (short*)region;              // 2 x 8M bf16 = 8,388,608 f

    dim3 blk(256);

    convert_w_kernel<<<dim3(9, 32), blk, 0, stream>>>(Wq, Wk, Wt, Psink);
    vproj_kernel<<<dim3(64, 32), blk, 0, stream>>>(x, Wv, bv, vt, xb);
    qkproj_kernel<<<dim3(9, 32, 4), blk, 0, stream>>>(xb, Wt, qkpart);
    convert_qk_kernel<<<dim3(1152), blk, 0, stream>>>(qkpart, bq, bk, qkb);
    qk_s_kernel<<<dim3(16, 16, 2), blk, 0, stream>>>(qkb, Sb);
    softmax_avg_kernel<<<dim3(1024, 2), blk, 0, stream>>>(Sb, P);
    sink_kernel<<<dim3(64), blk, 0, stream>>>(sq, qkb, Psink);
    sinky_kernel<<<dim3(512, 2), blk, 0, stream>>>(Psink, vt, Ysink);
    y_fused_kernel<<<dim3(32, 8, 2), blk, 0, stream>>>(
        P, vt, Ysink, Wo, bo, x, out);
}